// Round 1
// baseline (245.860 us; speedup 1.0000x reference)
//
#include <hip/hip_runtime.h>
#include <math.h>

#define L_SEQ 32768
#define NS 128
#define TS 2048   // conv tile / chunk size

// ---------------------------------------------------------------------------
// Build T = alpha*(A + 2I), U1 = I + T, where alpha = (step/2)/(1+step).
// ---------------------------------------------------------------------------
__global__ __launch_bounds__(256) void build_T(const float* __restrict__ A,
                                               const float* __restrict__ lstep,
                                               float* __restrict__ T,
                                               float* __restrict__ U1) {
  int idx = blockIdx.x * 256 + threadIdx.x;
  if (idx >= NS * NS) return;
  int i = idx >> 7, j = idx & 127;
  float step = expf(lstep[0]);
  float alpha = 0.5f * step / (1.0f + step);
  float g = A[idx] + ((i == j) ? 2.0f : 0.0f);
  float t = alpha * g;
  T[idx] = t;
  U1[idx] = t + ((i == j) ? 1.0f : 0.0f);
}

// ---------------------------------------------------------------------------
// Generic small GEMM, two independent jobs per launch (block-split).
// C[i*ldc+j] = epilogue( sum_k A[i*128+k]*B[k*ldb+j] ), P = 1<<lgP.
// mode 0: out = acc
// mode 1: out = acc + A[i][j]                       (U12 = U1*T2 + U1)
// mode 2: out = acc + A[i][j] + B[i][j] + I         (U48 = T4*T8 + T4 + T8 + I)
// mode 3: out = (2/(1+step))*acc - I                (ab from U12*U48)
// ---------------------------------------------------------------------------
__global__ __launch_bounds__(256) void gemm2(
    const float* __restrict__ A1, const float* __restrict__ B1, float* __restrict__ C1,
    int M1, int lgP1, int ldb1, int ldc1, int mode1,
    const float* __restrict__ A2, const float* __restrict__ B2, float* __restrict__ C2,
    int M2, int lgP2, int ldb2, int ldc2, int mode2,
    int n1, const float* __restrict__ lstep) {
  int b = blockIdx.x;
  bool sec = (b >= n1);
  const float* Ap = sec ? A2 : A1;
  const float* Bp = sec ? B2 : B1;
  float* Cp = sec ? C2 : C1;
  int M   = sec ? M2 : M1;
  int lgP = sec ? lgP2 : lgP1;
  int ldb = sec ? ldb2 : ldb1;
  int ldc = sec ? ldc2 : ldc1;
  int mode = sec ? mode2 : mode1;
  int bid = sec ? (b - n1) : b;

  int idx = bid * 256 + threadIdx.x;
  int total = M << lgP;
  if (idx >= total) return;
  int i = idx >> lgP;
  int j = idx & ((1 << lgP) - 1);

  const float* Arow = Ap + i * NS;
  float acc = 0.f;
#pragma unroll 8
  for (int k = 0; k < NS; ++k) acc = fmaf(Arow[k], Bp[k * ldb + j], acc);

  float out;
  if (mode == 0) {
    out = acc;
  } else if (mode == 1) {
    out = acc + Arow[j];
  } else if (mode == 2) {
    out = acc + Arow[j] + Bp[i * ldb + j] + ((i == j) ? 1.f : 0.f);
  } else {  // mode 3
    float step = expf(lstep[0]);
    out = (2.f / (1.f + step)) * acc - ((i == j) ? 1.f : 0.f);
  }
  Cp[i * ldc + j] = out;
}

// ---------------------------------------------------------------------------
// prep: bb = (step/2)*(ab*B + B) -> R column 0 ; S row 0 = C.
// ---------------------------------------------------------------------------
__global__ __launch_bounds__(256) void prep(const float* __restrict__ ab,
                                            const float* __restrict__ B,
                                            const float* __restrict__ C,
                                            const float* __restrict__ lstep,
                                            float* __restrict__ R,
                                            float* __restrict__ S) {
  int t = threadIdx.x;
  if (t < NS) {
    float acc = 0.f;
    for (int k = 0; k < NS; ++k) acc = fmaf(ab[t * NS + k], B[k], acc);
    float step = expf(lstep[0]);
    R[t * 256] = 0.5f * step * (acc + B[t]);
  } else if (t < 2 * NS) {
    int j = t - NS;
    S[j] = C[j];
  }
}

// ---------------------------------------------------------------------------
// Conv partial: task (m, c), c <= m; computes partial y over output tile m
// from s-chunk c:  P[c][t] = sum_{s in chunk c} K[s] * u[t-s].
// 136 tasks, one block each, 256 thr, 8 outputs/thread, LDS staging.
// u indices < 0 are staged as 0 (handles s > t on the diagonal).
// ---------------------------------------------------------------------------
__global__ __launch_bounds__(256) void conv_partial(const float* __restrict__ u,
                                                    const float* __restrict__ Kv,
                                                    float* __restrict__ Pp) {
  __shared__ __align__(16) float ks[TS];
  __shared__ __align__(16) float us[2 * TS];

  int bid = blockIdx.x;
  int m = 0;
  while ((m + 1) * (m + 2) / 2 <= bid) m++;
  int c = bid - m * (m + 1) / 2;
  int w0 = (m - c) * TS - TS;  // us[li] = u[w0 + li]
  int tid = threadIdx.x;

  for (int idx = tid; idx < TS; idx += 256) ks[idx] = Kv[c * TS + idx];
  for (int idx = tid; idx < 2 * TS; idx += 256) {
    int gi = w0 + idx;
    us[idx] = (gi >= 0) ? u[gi] : 0.f;
  }
  __syncthreads();

  float acc[8];
#pragma unroll
  for (int i = 0; i < 8; ++i) acc[i] = 0.f;

  int tb = tid << 3;  // first of this thread's 8 outputs (within tile)

  for (int s8 = 0; s8 < TS; s8 += 8) {
    float4 k0 = *(const float4*)&ks[s8];
    float4 k1 = *(const float4*)&ks[s8 + 4];
    int base = TS + tb - s8;  // local index of u[t0 - s8]
    float4 ua = *(const float4*)&us[base - 8];
    float4 ub = *(const float4*)&us[base - 4];
    float4 uc = *(const float4*)&us[base];
    float4 ud = *(const float4*)&us[base + 4];
    // w[x] = u[t0 - s8 - 8 + x],  x = 0..15
    float w[16] = {ua.x, ua.y, ua.z, ua.w, ub.x, ub.y, ub.z, ub.w,
                   uc.x, uc.y, uc.z, uc.w, ud.x, ud.y, ud.z, ud.w};
    float kk[8] = {k0.x, k0.y, k0.z, k0.w, k1.x, k1.y, k1.z, k1.w};
#pragma unroll
    for (int ds = 0; ds < 8; ++ds) {
#pragma unroll
      for (int i = 0; i < 8; ++i) acc[i] = fmaf(kk[ds], w[8 + i - ds], acc[i]);
    }
  }

  float* dst = Pp + c * L_SEQ + m * TS + tb;
  *(float4*)&dst[0] = make_float4(acc[0], acc[1], acc[2], acc[3]);
  *(float4*)&dst[4] = make_float4(acc[4], acc[5], acc[6], acc[7]);
}

// ---------------------------------------------------------------------------
// reduce: y[t] = D*u[t] + sum_{c<=t>>11} P[c][t]
// ---------------------------------------------------------------------------
__global__ __launch_bounds__(256) void reduce_k(const float* __restrict__ Pp,
                                                const float* __restrict__ u,
                                                const float* __restrict__ D,
                                                float* __restrict__ y) {
  int t = blockIdx.x * 256 + threadIdx.x;
  if (t >= L_SEQ) return;
  int mmax = t >> 11;
  float acc = D[0] * u[t];
  for (int c = 0; c <= mmax; ++c) acc += Pp[c * L_SEQ + t];
  y[t] = acc;
}

// ---------------------------------------------------------------------------
// host side
// ---------------------------------------------------------------------------
static inline void launch_gemm1(hipStream_t s, const float* A, const float* B, float* C,
                                int M, int lgP, int ldb, int ldc, int mode,
                                const float* lstep) {
  int n1 = ((M << lgP) + 255) >> 8;
  hipLaunchKernelGGL(gemm2, dim3(n1), dim3(256), 0, s,
                     A, B, C, M, lgP, ldb, ldc, mode,
                     (const float*)nullptr, (const float*)nullptr, (float*)nullptr,
                     0, 0, 0, 0, 0, n1, lstep);
}

static inline void launch_gemm2j(hipStream_t s,
                                 const float* A1, const float* B1, float* C1,
                                 int M1, int lgP1, int ldb1, int ldc1, int mode1,
                                 const float* A2, const float* B2, float* C2,
                                 int M2, int lgP2, int ldb2, int ldc2, int mode2,
                                 const float* lstep) {
  int n1 = ((M1 << lgP1) + 255) >> 8;
  int n2 = ((M2 << lgP2) + 255) >> 8;
  hipLaunchKernelGGL(gemm2, dim3(n1 + n2), dim3(256), 0, s,
                     A1, B1, C1, M1, lgP1, ldb1, ldc1, mode1,
                     A2, B2, C2, M2, lgP2, ldb2, ldc2, mode2, n1, lstep);
}

extern "C" void kernel_launch(void* const* d_in, const int* in_sizes, int n_in,
                              void* d_out, int out_size, void* d_ws, size_t ws_size,
                              hipStream_t stream) {
  (void)in_sizes; (void)n_in; (void)out_size; (void)ws_size;
  const float* u     = (const float*)d_in[0];
  const float* A     = (const float*)d_in[1];
  const float* B     = (const float*)d_in[2];
  const float* C     = (const float*)d_in[3];
  const float* D     = (const float*)d_in[4];
  const float* lstep = (const float*)d_in[5];
  float* y  = (float*)d_out;
  float* ws = (float*)d_ws;

  float* T   = ws + 0;
  float* U1  = ws + 16384;
  float* T2  = ws + 32768;
  float* T4  = ws + 49152;
  float* T8  = ws + 65536;
  float* U12 = ws + 81920;
  float* U48 = ws + 98304;
  float* ab  = ws + 114688;
  float* pwA = ws + 131072;
  float* pwB = ws + 147456;
  float* R   = ws + 163840;   // 128 x 256, row-major
  float* S   = ws + 196608;   // 128 x 128, row-major
  float* Kv  = ws + 212992;   // 32768 = 128 x 256 (t1-major)
  float* Pp  = ws + 245760;   // 16 x 32768 partials

  // --- inverse via Neumann product: bl*(1+step) = (I+T)(I+T^2)(I+T^4)(I+T^8)
  hipLaunchKernelGGL(build_T, dim3(64), dim3(256), 0, stream, A, lstep, T, U1);
  launch_gemm1(stream, T, T, T2, 128, 7, 128, 128, 0, lstep);            // T2 = T*T
  launch_gemm2j(stream, T2, T2, T4, 128, 7, 128, 128, 0,                 // T4 = T2*T2
                U1, T2, U12, 128, 7, 128, 128, 1, lstep);                // U12 = U1*T2 + U1
  launch_gemm1(stream, T4, T4, T8, 128, 7, 128, 128, 0, lstep);          // T8 = T4*T4
  launch_gemm1(stream, T4, T8, U48, 128, 7, 128, 128, 2, lstep);         // U48 = T4*T8+T4+T8+I
  launch_gemm1(stream, U12, U48, ab, 128, 7, 128, 128, 3, lstep);        // ab = 2*bl - I
  hipLaunchKernelGGL(prep, dim3(1), dim3(256), 0, stream, ab, B, C, lstep, R, S);

  // pw(k) = ab^(2^k)
  auto pw = [&](int k) -> float* { return k == 0 ? ab : ((k & 1) ? pwA : pwB); };

  // --- R doubling: R[:, 2^k + j] = pw(k) * R[:, j], plus squaring chain
  for (int k = 0; k < 8; ++k) {
    launch_gemm2j(stream, pw(k), R, R + (1 << k), 128, k, 256, 256, 0,
                  pw(k), pw(k), pw(k + 1), 128, 7, 128, 128, 0, lstep);
  }
  // --- S doubling: S[2^k + i, :] = S[i, :] * pw(8+k)
  for (int k = 0; k < 7; ++k) {
    if (k < 6) {
      launch_gemm2j(stream, S, pw(8 + k), S + (1 << k) * 128, 1 << k, 7, 128, 128, 0,
                    pw(8 + k), pw(8 + k), pw(9 + k), 128, 7, 128, 128, 0, lstep);
    } else {
      launch_gemm1(stream, S, pw(8 + k), S + (1 << k) * 128, 1 << k, 7, 128, 128, 0, lstep);
    }
  }

  // --- K = S * R  (K[t1*256 + t0])
  launch_gemm1(stream, S, R, Kv, 128, 8, 256, 256, 0, lstep);

  // --- causal convolution + D*u
  hipLaunchKernelGGL(conv_partial, dim3(136), dim3(256), 0, stream, u, Kv, Pp);
  hipLaunchKernelGGL(reduce_k, dim3(128), dim3(256), 0, stream, Pp, u, D, y);
}